// Round 6
// baseline (884.327 us; speedup 1.0000x reference)
//
#include <hip/hip_runtime.h>
#include <math.h>

#define NTOK 8192
#define DMODEL 1024
#define DFF 4096
#define NEXP 8
#define TILE 256
#define MAXTILES 72
#define MAXROWS (MAXTILES * TILE)
#define MOE_EPS 1e-9f
#define KCHUNK 2

typedef unsigned short u16;
typedef __bf16 bf16x8 __attribute__((ext_vector_type(8)));
typedef float f32x4 __attribute__((ext_vector_type(4)));

struct Ctrl {
    int counts[NEXP];
    int fill[NEXP];
    int padded_off[NEXP];
    int n_tiles;
    int tile_expert[MAXTILES];
    int tile_base[MAXTILES];
    int tile_valid[MAXTILES];
    float imp[NEXP];
    float zacc;
};

__device__ __forceinline__ u16 f2bf(float f) {
    unsigned u = __float_as_uint(f);
    unsigned r = u + 0x7fffu + ((u >> 16) & 1u);
    return (u16)(r >> 16);
}

__device__ __forceinline__ void load16(const void* g, void* l) {
    __builtin_amdgcn_global_load_lds((__attribute__((address_space(1))) void*)g,
                                     (__attribute__((address_space(3))) void*)l,
                                     16, 0, 0);
}

// fast GELU: h*sigmoid(1.59577h+0.071355h^3) (tanh-form), |err| < 1e-3
__device__ __forceinline__ float gelu_fast(float h) {
    float u = h * (1.5957691216f + 0.0713548162f * h * h);
    return h / (1.f + __expf(-u));
}

// ---------------- fp32 -> bf16 convert (w1, w2) ----------------
__global__ __launch_bounds__(256) void k_convert(const float* __restrict__ src,
                                                 u16* __restrict__ dst, int n4) {
    int i = blockIdx.x * 256 + threadIdx.x;
    int stride = gridDim.x * 256;
    for (; i < n4; i += stride) {
        float4 v = ((const float4*)src)[i];
        ushort4 o;
        o.x = f2bf(v.x); o.y = f2bf(v.y); o.z = f2bf(v.z); o.w = f2bf(v.w);
        ((ushort4*)dst)[i] = o;
    }
}

// ---------------- router (+ fused x->bf16 conversion) ----------------
__global__ __launch_bounds__(256) void k_router(const float* __restrict__ x,
                                                const float* __restrict__ rw,
                                                u16* __restrict__ xb,
                                                int* __restrict__ top_idx,
                                                float* __restrict__ top_w,
                                                Ctrl* __restrict__ ctrl) {
    __shared__ float srw[NEXP * DMODEL];
    __shared__ float simp[NEXP];
    __shared__ float szl;
    int tid = threadIdx.x;
    for (int i = tid; i < NEXP * DMODEL / 4; i += 256)
        ((float4*)srw)[i] = ((const float4*)rw)[i];
    if (tid < NEXP) simp[tid] = 0.f;
    if (tid == 0) szl = 0.f;
    __syncthreads();

    int lane = tid & 63;
    int n = blockIdx.x * 4 + (tid >> 6);
    float p[NEXP];
#pragma unroll
    for (int e = 0; e < NEXP; ++e) p[e] = 0.f;
    const float4* xr = (const float4*)(x + (size_t)n * DMODEL);
    u16 xs[16];
#pragma unroll
    for (int j = 0; j < 4; ++j) {
        float4 xv = xr[lane * 4 + j];
        int d = (lane * 4 + j) * 4;
        xs[j * 4 + 0] = f2bf(xv.x);
        xs[j * 4 + 1] = f2bf(xv.y);
        xs[j * 4 + 2] = f2bf(xv.z);
        xs[j * 4 + 3] = f2bf(xv.w);
#pragma unroll
        for (int e = 0; e < NEXP; ++e) {
            const float* r = srw + e * DMODEL + d;
            p[e] += xv.x * r[0] + xv.y * r[1] + xv.z * r[2] + xv.w * r[3];
        }
    }
    // write 16 bf16 (2 x 16B) for this token row
    {
        uint4* dst = (uint4*)(xb + (size_t)n * DMODEL + lane * 16);
        dst[0] = ((const uint4*)xs)[0];
        dst[1] = ((const uint4*)xs)[1];
    }
#pragma unroll
    for (int e = 0; e < NEXP; ++e) {
#pragma unroll
        for (int off = 32; off > 0; off >>= 1) p[e] += __shfl_xor(p[e], off);
    }
    if (lane == 0) {
        float m = p[0];
#pragma unroll
        for (int e = 1; e < NEXP; ++e) m = fmaxf(m, p[e]);
        float pr[NEXP];
        float s = 0.f;
#pragma unroll
        for (int e = 0; e < NEXP; ++e) { pr[e] = expf(p[e] - m); s += pr[e]; }
        float inv = 1.f / s;
#pragma unroll
        for (int e = 0; e < NEXP; ++e) pr[e] *= inv;
        float lse = m + logf(s);
        int i0 = 0; float v0 = pr[0];
#pragma unroll
        for (int e = 1; e < NEXP; ++e) if (pr[e] > v0) { v0 = pr[e]; i0 = e; }
        int i1 = -1; float v1 = -1.f;
#pragma unroll
        for (int e = 0; e < NEXP; ++e) if (e != i0 && pr[e] > v1) { v1 = pr[e]; i1 = e; }
        float den = v0 + v1 + MOE_EPS;
        top_idx[n * 2] = i0;
        top_idx[n * 2 + 1] = i1;
        top_w[n * 2] = v0 / den;
        top_w[n * 2 + 1] = v1 / den;
#pragma unroll
        for (int e = 0; e < NEXP; ++e) atomicAdd(&simp[e], pr[e]);
        atomicAdd(&szl, lse * lse);
    }
    __syncthreads();
    if (tid < NEXP) atomicAdd(&ctrl->imp[tid], simp[tid]);
    if (tid == 255) atomicAdd(&ctrl->zacc, szl);
}

// ---------------- build schedule ----------------
__global__ __launch_bounds__(256) void k_build(const int* __restrict__ top_idx,
                                               Ctrl* __restrict__ ctrl,
                                               int* __restrict__ tok_idx,
                                               float* __restrict__ tok_w) {
    __shared__ int cnt[NEXP];
    __shared__ int off[NEXP];
    __shared__ int tiles[NEXP];
    int tid = threadIdx.x;
    if (tid < NEXP) cnt[tid] = 0;
    __syncthreads();
    for (int i = tid; i < NTOK * 2; i += 256) atomicAdd(&cnt[top_idx[i]], 1);
    __syncthreads();
    if (tid == 0) {
        int o = 0, t = 0;
        for (int e = 0; e < NEXP; ++e) {
            int c = cnt[e];
            int te = (c + TILE - 1) / TILE;
            ctrl->counts[e] = c;
            ctrl->padded_off[e] = o;
            off[e] = o;
            tiles[e] = te;
            for (int i = 0; i < te; ++i) {
                ctrl->tile_expert[t] = e;
                ctrl->tile_base[t] = o + i * TILE;
                int v = c - i * TILE;
                ctrl->tile_valid[t] = v > TILE ? TILE : v;
                ++t;
            }
            o += te * TILE;
        }
        ctrl->n_tiles = t;
    }
    __syncthreads();
    for (int e = 0; e < NEXP; ++e) {
        int start = off[e] + cnt[e];
        int end = off[e] + tiles[e] * TILE;
        for (int i = start + tid; i < end; i += 256) {
            tok_idx[i] = 0;
            tok_w[i] = 0.f;
        }
    }
}

// ---------------- fill token lists ----------------
__global__ __launch_bounds__(256) void k_fill(const int* __restrict__ top_idx,
                                              const float* __restrict__ top_w,
                                              Ctrl* __restrict__ ctrl,
                                              int* __restrict__ tok_idx,
                                              float* __restrict__ tok_w) {
    int n = blockIdx.x * 256 + threadIdx.x;
    if (n >= NTOK) return;
#pragma unroll
    for (int k = 0; k < 2; ++k) {
        int e = top_idx[n * 2 + k];
        int pos = atomicAdd(&ctrl->fill[e], 1);
        int slot = ctrl->padded_off[e] + pos;
        tok_idx[slot] = n;
        tok_w[slot] = top_w[n * 2 + k];
    }
}

// ============ GEMM1: H = gelu(Xg @ w1^T + b1) [256x256, 2-deep counted vmcnt] ============
__global__ __launch_bounds__(512, 2) void k_gemm1(const u16* __restrict__ xb,
                                                  const u16* __restrict__ w1b,
                                                  const float* __restrict__ b1,
                                                  const int* __restrict__ tok_idx,
                                                  const Ctrl* __restrict__ ctrl,
                                                  u16* __restrict__ H) {
    int t = blockIdx.x;
    if (t >= ctrl->n_tiles) return;
    int e = ctrl->tile_expert[t];
    int rbase = ctrl->tile_base[t];
    int n0 = blockIdx.y * TILE;

    __shared__ __align__(16) u16 sA[2][TILE * 64];
    __shared__ __align__(16) u16 sB[2][TILE * 64];

    int tid = threadIdx.x;
    const u16* aSrc[4];
    const u16* bSrc[4];
#pragma unroll
    for (int q = 0; q < 4; ++q) {
        int flat = q * 512 + tid;
        int row = flat >> 3;
        int c8 = (((flat & 7) ^ (row & 7))) * 8;   // inverse-swizzled source chunk
        aSrc[q] = xb + (size_t)tok_idx[rbase + row] * DMODEL + c8;
        bSrc[q] = w1b + (size_t)e * DFF * DMODEL + (size_t)(n0 + row) * DMODEL + c8;
    }

    int lane = tid & 63, w = tid >> 6;
    int wr = w >> 2, wc = w & 3;           // 2M x 4N waves; wave tile 128x64
    int l15 = lane & 15, lg = lane >> 4;
    int xr7 = l15 & 7;

    f32x4 acc[8][4];
#pragma unroll
    for (int m = 0; m < 8; ++m)
#pragma unroll
        for (int n = 0; n < 4; ++n) acc[m][n] = (f32x4){0.f, 0.f, 0.f, 0.f};

    int arow[8], brow[4], cs[2];
#pragma unroll
    for (int m = 0; m < 8; ++m) arow[m] = (wr * 128 + m * 16 + l15) * 64;
#pragma unroll
    for (int n = 0; n < 4; ++n) brow[n] = (wc * 64 + n * 16 + l15) * 64;
    cs[0] = ((lg + 0) ^ xr7) * 8;
    cs[1] = ((lg + 4) ^ xr7) * 8;

#define STAGE1(buf, kt)                                                      \
    do {                                                                     \
        _Pragma("unroll") for (int q = 0; q < 4; ++q) {                      \
            load16(aSrc[q] + (kt) * 64, &sA[buf][(q * 512 + tid) * 8]);      \
            load16(bSrc[q] + (kt) * 64, &sB[buf][(q * 512 + tid) * 8]);      \
        }                                                                    \
    } while (0)

    const int NK = DMODEL / 64;
    STAGE1(0, 0);
    STAGE1(1, 1);
    for (int kt = 0; kt < NK; ++kt) {
        int p = kt & 1;
        if (kt < NK - 1) {
            asm volatile("s_waitcnt vmcnt(8)" ::: "memory");
        } else {
            asm volatile("s_waitcnt vmcnt(0)" ::: "memory");
        }
        __builtin_amdgcn_s_barrier();
        __builtin_amdgcn_sched_barrier(0);
        const u16* pA = sA[p];
        const u16* pB = sB[p];
#pragma unroll
        for (int kk = 0; kk < 2; ++kk) {
            bf16x8 af[8], bfr[4];
#pragma unroll
            for (int m = 0; m < 8; ++m) af[m] = *(const bf16x8*)(pA + arow[m] + cs[kk]);
#pragma unroll
            for (int n = 0; n < 4; ++n) bfr[n] = *(const bf16x8*)(pB + brow[n] + cs[kk]);
            __builtin_amdgcn_s_setprio(1);
#pragma unroll
            for (int m = 0; m < 8; ++m)
#pragma unroll
                for (int n = 0; n < 4; ++n)
                    acc[m][n] = __builtin_amdgcn_mfma_f32_16x16x32_bf16(af[m], bfr[n],
                                                                        acc[m][n], 0, 0, 0);
            __builtin_amdgcn_s_setprio(0);
        }
        __builtin_amdgcn_sched_barrier(0);
        __builtin_amdgcn_s_barrier();      // all waves done reading buf p
        if (kt + 2 < NK) STAGE1(p, kt + 2);
    }
#undef STAGE1

    float bias[4];
#pragma unroll
    for (int n = 0; n < 4; ++n) bias[n] = b1[e * DFF + n0 + wc * 64 + n * 16 + l15];
#pragma unroll
    for (int m = 0; m < 8; ++m)
#pragma unroll
        for (int n = 0; n < 4; ++n) {
            int gcol = n0 + wc * 64 + n * 16 + l15;
#pragma unroll
            for (int r = 0; r < 4; ++r) {
                int grow = wr * 128 + m * 16 + lg * 4 + r;
                float h = acc[m][n][r] + bias[n];
                H[(size_t)(rbase + grow) * DFF + gcol] = f2bf(gelu_fast(h));
            }
        }
}

// ============ GEMM2: y += w * (H @ w2^T + b2) [256x256, split-K x2, counted vmcnt] ============
__global__ __launch_bounds__(512, 2) void k_gemm2(const u16* __restrict__ H,
                                                  const u16* __restrict__ w2b,
                                                  const float* __restrict__ b2,
                                                  const int* __restrict__ tok_idx,
                                                  const float* __restrict__ tok_w,
                                                  const Ctrl* __restrict__ ctrl,
                                                  float* __restrict__ y) {
    int t = blockIdx.x;
    if (t >= ctrl->n_tiles) return;
    int e = ctrl->tile_expert[t];
    int rbase = ctrl->tile_base[t];
    int valid = ctrl->tile_valid[t];
    int n0 = blockIdx.y * TILE;
    int chunk = blockIdx.z;
    const int NK = DFF / 64 / KCHUNK;          // 32 K-tiles per chunk
    int kbase = chunk * NK * 64;               // element offset in K

    __shared__ __align__(16) u16 sA[2][TILE * 64];
    __shared__ __align__(16) u16 sB[2][TILE * 64];

    int tid = threadIdx.x;
    const u16* aSrc[4];
    const u16* bSrc[4];
#pragma unroll
    for (int q = 0; q < 4; ++q) {
        int flat = q * 512 + tid;
        int row = flat >> 3;
        int c8 = (((flat & 7) ^ (row & 7))) * 8;
        aSrc[q] = H + (size_t)(rbase + row) * DFF + kbase + c8;
        bSrc[q] = w2b + (size_t)e * DMODEL * DFF + (size_t)(n0 + row) * DFF + kbase + c8;
    }

    int lane = tid & 63, w = tid >> 6;
    int wr = w >> 2, wc = w & 3;
    int l15 = lane & 15, lg = lane >> 4;
    int xr7 = l15 & 7;

    f32x4 acc[8][4];
#pragma unroll
    for (int m = 0; m < 8; ++m)
#pragma unroll
        for (int n = 0; n < 4; ++n) acc[m][n] = (f32x4){0.f, 0.f, 0.f, 0.f};

    int arow[8], brow[4], cs[2];
#pragma unroll
    for (int m = 0; m < 8; ++m) arow[m] = (wr * 128 + m * 16 + l15) * 64;
#pragma unroll
    for (int n = 0; n < 4; ++n) brow[n] = (wc * 64 + n * 16 + l15) * 64;
    cs[0] = ((lg + 0) ^ xr7) * 8;
    cs[1] = ((lg + 4) ^ xr7) * 8;

#define STAGE2(buf, kt)                                                      \
    do {                                                                     \
        _Pragma("unroll") for (int q = 0; q < 4; ++q) {                      \
            load16(aSrc[q] + (kt) * 64, &sA[buf][(q * 512 + tid) * 8]);      \
            load16(bSrc[q] + (kt) * 64, &sB[buf][(q * 512 + tid) * 8]);      \
        }                                                                    \
    } while (0)

    STAGE2(0, 0);
    STAGE2(1, 1);
    for (int kt = 0; kt < NK; ++kt) {
        int p = kt & 1;
        if (kt < NK - 1) {
            asm volatile("s_waitcnt vmcnt(8)" ::: "memory");
        } else {
            asm volatile("s_waitcnt vmcnt(0)" ::: "memory");
        }
        __builtin_amdgcn_s_barrier();
        __builtin_amdgcn_sched_barrier(0);
        const u16* pA = sA[p];
        const u16* pB = sB[p];
#pragma unroll
        for (int kk = 0; kk < 2; ++kk) {
            bf16x8 af[8], bfr[4];
#pragma unroll
            for (int m = 0; m < 8; ++m) af[m] = *(const bf16x8*)(pA + arow[m] + cs[kk]);
#pragma unroll
            for (int n = 0; n < 4; ++n) bfr[n] = *(const bf16x8*)(pB + brow[n] + cs[kk]);
            __builtin_amdgcn_s_setprio(1);
#pragma unroll
            for (int m = 0; m < 8; ++m)
#pragma unroll
                for (int n = 0; n < 4; ++n)
                    acc[m][n] = __builtin_amdgcn_mfma_f32_16x16x32_bf16(af[m], bfr[n],
                                                                        acc[m][n], 0, 0, 0);
            __builtin_amdgcn_s_setprio(0);
        }
        __builtin_amdgcn_sched_barrier(0);
        __builtin_amdgcn_s_barrier();
        if (kt + 2 < NK) STAGE2(p, kt + 2);
    }
#undef STAGE2

    float bias[4];
#pragma unroll
    for (int n = 0; n < 4; ++n)
        bias[n] = (chunk == 0) ? b2[e * DMODEL + n0 + wc * 64 + n * 16 + l15] : 0.f;
#pragma unroll
    for (int m = 0; m < 8; ++m)
#pragma unroll
        for (int n = 0; n < 4; ++n) {
            int gcol = n0 + wc * 64 + n * 16 + l15;
#pragma unroll
            for (int r = 0; r < 4; ++r) {
                int grow = wr * 128 + m * 16 + lg * 4 + r;
                if (grow < valid) {
                    int slot = rbase + grow;
                    int tok = tok_idx[slot];
                    float wgt = tok_w[slot];
                    unsafeAtomicAdd(&y[(size_t)tok * DMODEL + gcol],
                                    wgt * (acc[m][n][r] + bias[n]));
                }
            }
        }
}

// ---------------- finalize ----------------
__global__ void k_final(const Ctrl* __restrict__ ctrl, float* __restrict__ out) {
    if (blockIdx.x == 0 && threadIdx.x == 0) {
        float imp[NEXP], ld[NEXP];
        float imps = 0.f, loads = 0.f;
        for (int e = 0; e < NEXP; ++e) {
            imp[e] = ctrl->imp[e];
            ld[e] = (float)ctrl->counts[e];
            imps += imp[e];
            loads += ld[e];
        }
        float bal = 0.f;
        for (int e = 0; e < NEXP; ++e)
            bal += (imp[e] / (imps + MOE_EPS)) * (ld[e] / (loads + MOE_EPS));
        bal *= (float)NEXP;
        float z = ctrl->zacc / (float)NTOK;
        float aux = 0.01f * bal + 0.001f * z;
        size_t base = (size_t)NTOK * DMODEL;
        out[base] = aux;
        for (int e = 0; e < NEXP; ++e) out[base + 1 + e] = ld[e];
        for (int e = 0; e < NEXP; ++e) out[base + 9 + e] = imp[e];
    }
}

extern "C" void kernel_launch(void* const* d_in, const int* in_sizes, int n_in,
                              void* d_out, int out_size, void* d_ws, size_t ws_size,
                              hipStream_t stream) {
    (void)in_sizes; (void)n_in; (void)out_size; (void)ws_size;
    const float* x  = (const float*)d_in[0];
    const float* rw = (const float*)d_in[1];
    const float* w1 = (const float*)d_in[2];
    const float* b1 = (const float*)d_in[3];
    const float* w2 = (const float*)d_in[4];
    const float* b2 = (const float*)d_in[5];
    float* out = (float*)d_out;

    char* p = (char*)d_ws;
    Ctrl* ctrl = (Ctrl*)p;          p += 4096;
    u16* xb    = (u16*)p;           p += (size_t)NTOK * DMODEL * 2;
    u16* w1b   = (u16*)p;           p += (size_t)NEXP * DFF * DMODEL * 2;
    u16* w2b   = (u16*)p;           p += (size_t)NEXP * DMODEL * DFF * 2;
    u16* Hbuf  = (u16*)p;           p += (size_t)MAXROWS * DFF * 2;
    int* tok_idx = (int*)p;         p += (size_t)MAXROWS * 4;
    float* tok_w = (float*)p;       p += (size_t)MAXROWS * 4;
    int* tIdx  = (int*)p;           p += (size_t)NTOK * 2 * 4;
    float* tW  = (float*)p;         p += (size_t)NTOK * 2 * 4;

    hipMemsetAsync(ctrl, 0, sizeof(Ctrl), stream);
    hipMemsetAsync(d_out, 0, (size_t)NTOK * DMODEL * sizeof(float), stream);

    k_convert<<<2048, 256, 0, stream>>>(w1, w1b, NEXP * DFF * DMODEL / 4);
    k_convert<<<2048, 256, 0, stream>>>(w2, w2b, NEXP * DMODEL * DFF / 4);

    k_router<<<NTOK / 4, 256, 0, stream>>>(x, rw, xb, tIdx, tW, ctrl);
    k_build<<<1, 256, 0, stream>>>(tIdx, ctrl, tok_idx, tok_w);
    k_fill<<<NTOK / 256, 256, 0, stream>>>(tIdx, tW, ctrl, tok_idx, tok_w);

    dim3 g1(MAXTILES, DFF / TILE);
    k_gemm1<<<g1, 512, 0, stream>>>(xb, w1b, b1, tok_idx, ctrl, Hbuf);

    dim3 g2(MAXTILES, DMODEL / TILE, KCHUNK);
    k_gemm2<<<g2, 512, 0, stream>>>(Hbuf, w2b, b2, tok_idx, tok_w, ctrl, out);

    k_final<<<1, 64, 0, stream>>>(ctrl, out);
}

// Round 7
// 841.891 us; speedup vs baseline: 1.0504x; 1.0504x over previous
//
#include <hip/hip_runtime.h>
#include <math.h>

#define NTOK 8192
#define DMODEL 1024
#define DFF 4096
#define NEXP 8
#define TILE 256
#define MAXTILES 72
#define MAXROWS (MAXTILES * TILE)
#define MOE_EPS 1e-9f
#define REG 8192  // u16 elements per (dbuf,kk) region: 256 rows * 32 cols

typedef unsigned short u16;
typedef __bf16 bf16x8 __attribute__((ext_vector_type(8)));
typedef float f32x4 __attribute__((ext_vector_type(4)));

struct Ctrl {
    int counts[NEXP];
    int fill[NEXP];
    int padded_off[NEXP];
    int n_tiles;
    int tile_expert[MAXTILES];
    int tile_base[MAXTILES];
    int tile_valid[MAXTILES];
    float imp[NEXP];
    float zacc;
};

__device__ __forceinline__ u16 f2bf(float f) {
    unsigned u = __float_as_uint(f);
    unsigned r = u + 0x7fffu + ((u >> 16) & 1u);
    return (u16)(r >> 16);
}

__device__ __forceinline__ void load16(const void* g, void* l) {
    __builtin_amdgcn_global_load_lds((__attribute__((address_space(1))) void*)g,
                                     (__attribute__((address_space(3))) void*)l,
                                     16, 0, 0);
}

// fast GELU: h*sigmoid(1.59577h+0.071355h^3) (tanh-form), |err| < 1e-3
__device__ __forceinline__ float gelu_fast(float h) {
    float u = h * (1.5957691216f + 0.0713548162f * h * h);
    return h / (1.f + __expf(-u));
}

// ---------------- fp32 -> bf16 convert (w1, w2) ----------------
__global__ __launch_bounds__(256) void k_convert(const float* __restrict__ src,
                                                 u16* __restrict__ dst, int n4) {
    int i = blockIdx.x * 256 + threadIdx.x;
    int stride = gridDim.x * 256;
    for (; i < n4; i += stride) {
        float4 v = ((const float4*)src)[i];
        ushort4 o;
        o.x = f2bf(v.x); o.y = f2bf(v.y); o.z = f2bf(v.z); o.w = f2bf(v.w);
        ((ushort4*)dst)[i] = o;
    }
}

// ---------------- router (+ fused x->bf16 conversion) ----------------
__global__ __launch_bounds__(256) void k_router(const float* __restrict__ x,
                                                const float* __restrict__ rw,
                                                u16* __restrict__ xb,
                                                int* __restrict__ top_idx,
                                                float* __restrict__ top_w,
                                                Ctrl* __restrict__ ctrl) {
    __shared__ float srw[NEXP * DMODEL];
    __shared__ float simp[NEXP];
    __shared__ float szl;
    int tid = threadIdx.x;
    for (int i = tid; i < NEXP * DMODEL / 4; i += 256)
        ((float4*)srw)[i] = ((const float4*)rw)[i];
    if (tid < NEXP) simp[tid] = 0.f;
    if (tid == 0) szl = 0.f;
    __syncthreads();

    int lane = tid & 63;
    int n = blockIdx.x * 4 + (tid >> 6);
    float p[NEXP];
#pragma unroll
    for (int e = 0; e < NEXP; ++e) p[e] = 0.f;
    const float4* xr = (const float4*)(x + (size_t)n * DMODEL);
    u16 xs[16];
#pragma unroll
    for (int j = 0; j < 4; ++j) {
        float4 xv = xr[lane * 4 + j];
        int d = (lane * 4 + j) * 4;
        xs[j * 4 + 0] = f2bf(xv.x);
        xs[j * 4 + 1] = f2bf(xv.y);
        xs[j * 4 + 2] = f2bf(xv.z);
        xs[j * 4 + 3] = f2bf(xv.w);
#pragma unroll
        for (int e = 0; e < NEXP; ++e) {
            const float* r = srw + e * DMODEL + d;
            p[e] += xv.x * r[0] + xv.y * r[1] + xv.z * r[2] + xv.w * r[3];
        }
    }
    {
        uint4* dst = (uint4*)(xb + (size_t)n * DMODEL + lane * 16);
        dst[0] = ((const uint4*)xs)[0];
        dst[1] = ((const uint4*)xs)[1];
    }
#pragma unroll
    for (int e = 0; e < NEXP; ++e) {
#pragma unroll
        for (int off = 32; off > 0; off >>= 1) p[e] += __shfl_xor(p[e], off);
    }
    if (lane == 0) {
        float m = p[0];
#pragma unroll
        for (int e = 1; e < NEXP; ++e) m = fmaxf(m, p[e]);
        float pr[NEXP];
        float s = 0.f;
#pragma unroll
        for (int e = 0; e < NEXP; ++e) { pr[e] = expf(p[e] - m); s += pr[e]; }
        float inv = 1.f / s;
#pragma unroll
        for (int e = 0; e < NEXP; ++e) pr[e] *= inv;
        float lse = m + logf(s);
        int i0 = 0; float v0 = pr[0];
#pragma unroll
        for (int e = 1; e < NEXP; ++e) if (pr[e] > v0) { v0 = pr[e]; i0 = e; }
        int i1 = -1; float v1 = -1.f;
#pragma unroll
        for (int e = 0; e < NEXP; ++e) if (e != i0 && pr[e] > v1) { v1 = pr[e]; i1 = e; }
        float den = v0 + v1 + MOE_EPS;
        top_idx[n * 2] = i0;
        top_idx[n * 2 + 1] = i1;
        top_w[n * 2] = v0 / den;
        top_w[n * 2 + 1] = v1 / den;
#pragma unroll
        for (int e = 0; e < NEXP; ++e) atomicAdd(&simp[e], pr[e]);
        atomicAdd(&szl, lse * lse);
    }
    __syncthreads();
    if (tid < NEXP) atomicAdd(&ctrl->imp[tid], simp[tid]);
    if (tid == 255) atomicAdd(&ctrl->zacc, szl);
}

// ---------------- build schedule ----------------
__global__ __launch_bounds__(256) void k_build(const int* __restrict__ top_idx,
                                               Ctrl* __restrict__ ctrl,
                                               int* __restrict__ tok_idx,
                                               float* __restrict__ tok_w) {
    __shared__ int cnt[NEXP];
    __shared__ int off[NEXP];
    __shared__ int tiles[NEXP];
    int tid = threadIdx.x;
    if (tid < NEXP) cnt[tid] = 0;
    __syncthreads();
    for (int i = tid; i < NTOK * 2; i += 256) atomicAdd(&cnt[top_idx[i]], 1);
    __syncthreads();
    if (tid == 0) {
        int o = 0, t = 0;
        for (int e = 0; e < NEXP; ++e) {
            int c = cnt[e];
            int te = (c + TILE - 1) / TILE;
            ctrl->counts[e] = c;
            ctrl->padded_off[e] = o;
            off[e] = o;
            tiles[e] = te;
            for (int i = 0; i < te; ++i) {
                ctrl->tile_expert[t] = e;
                ctrl->tile_base[t] = o + i * TILE;
                int v = c - i * TILE;
                ctrl->tile_valid[t] = v > TILE ? TILE : v;
                ++t;
            }
            o += te * TILE;
        }
        ctrl->n_tiles = t;
    }
    __syncthreads();
    for (int e = 0; e < NEXP; ++e) {
        int start = off[e] + cnt[e];
        int end = off[e] + tiles[e] * TILE;
        for (int i = start + tid; i < end; i += 256) {
            tok_idx[i] = 0;
            tok_w[i] = 0.f;
        }
    }
}

// ---------------- fill token lists ----------------
__global__ __launch_bounds__(256) void k_fill(const int* __restrict__ top_idx,
                                              const float* __restrict__ top_w,
                                              Ctrl* __restrict__ ctrl,
                                              int* __restrict__ tok_idx,
                                              float* __restrict__ tok_w) {
    int n = blockIdx.x * 256 + threadIdx.x;
    if (n >= NTOK) return;
#pragma unroll
    for (int k = 0; k < 2; ++k) {
        int e = top_idx[n * 2 + k];
        int pos = atomicAdd(&ctrl->fill[e], 1);
        int slot = ctrl->padded_off[e] + pos;
        tok_idx[slot] = n;
        tok_w[slot] = top_w[n * 2 + k];
    }
}

// ======== 4-phase K-loop shared structure (see ledger in comments) ========
// LDS: sA/sB[2 dbuf][2 kk][256 rows][32 cols] u16 (64KB each).
// Stage unit = one (matrix, kk) half: 16KB = 2 gload_lds/thread.
// Issue order per tile kt: ph0:(kt+1).Ak1  ph1:(kt+1).Bk1  ph2:(kt+2).Ak0  ph3:(kt+2).Bk0
// Every unit lands 6 phases before first read; steady-state guard vmcnt(8)
// at end of ph1 (covers this tile's k1) and ph3 (covers next tile's k0).
// Tail: ph1 guard vmcnt(0) when kt>NK-2; ph3 guard vmcnt(0) when kt>NK-3.
// Read swizzle: chunk' = lg ^ ((row>>1)&3)  -> worst 2-way bank alias (free).

#define KLOOP_PHASES(STA, STB, NK)                                                    \
    STA(0, 0, 0); STB(0, 0, 0); STA(0, 0, 1); STB(0, 0, 1); STA(1, 1, 0); STB(1, 1, 0); \
    asm volatile("s_waitcnt vmcnt(8)" ::: "memory");                                  \
    __builtin_amdgcn_s_barrier();                                                     \
    for (int kt = 0; kt < (NK); ++kt) {                                               \
        int p = kt & 1;                                                               \
        const u16* A0 = sA + (p * 2 + 0) * REG;                                       \
        const u16* A1 = sA + (p * 2 + 1) * REG;                                       \
        const u16* B0 = sB + (p * 2 + 0) * REG;                                       \
        const u16* B1 = sB + (p * 2 + 1) * REG;                                       \
        bf16x8 a[4], b[4];                                                            \
        /* ---- phase 0: kk0, m0-3 ---- */                                            \
        _Pragma("unroll") for (int m = 0; m < 4; ++m) a[m] = *(const bf16x8*)(A0 + aoff[m]); \
        _Pragma("unroll") for (int n = 0; n < 4; ++n) b[n] = *(const bf16x8*)(B0 + boff[n]); \
        if (kt + 1 < (NK)) { STA(p ^ 1, kt + 1, 1); }                                 \
        asm volatile("s_waitcnt lgkmcnt(0)" ::: "memory");                            \
        __builtin_amdgcn_sched_barrier(0);                                            \
        __builtin_amdgcn_s_setprio(1);                                                \
        _Pragma("unroll") for (int m = 0; m < 4; ++m)                                 \
            _Pragma("unroll") for (int n = 0; n < 4; ++n)                             \
                acc[m][n] = __builtin_amdgcn_mfma_f32_16x16x32_bf16(a[m], b[n], acc[m][n], 0, 0, 0); \
        __builtin_amdgcn_s_setprio(0);                                                \
        __builtin_amdgcn_sched_barrier(0);                                            \
        __builtin_amdgcn_s_barrier();                                                 \
        /* ---- phase 1: kk0, m4-7 ---- */                                            \
        _Pragma("unroll") for (int m = 0; m < 4; ++m) a[m] = *(const bf16x8*)(A0 + aoff[m + 4]); \
        if (kt + 1 < (NK)) { STB(p ^ 1, kt + 1, 1); }                                 \
        asm volatile("s_waitcnt lgkmcnt(0)" ::: "memory");                            \
        __builtin_amdgcn_sched_barrier(0);                                            \
        __builtin_amdgcn_s_setprio(1);                                                \
        _Pragma("unroll") for (int m = 0; m < 4; ++m)                                 \
            _Pragma("unroll") for (int n = 0; n < 4; ++n)                             \
                acc[m + 4][n] = __builtin_amdgcn_mfma_f32_16x16x32_bf16(a[m], b[n], acc[m + 4][n], 0, 0, 0); \
        __builtin_amdgcn_s_setprio(0);                                                \
        __builtin_amdgcn_sched_barrier(0);                                            \
        if (kt <= (NK) - 2) asm volatile("s_waitcnt vmcnt(8)" ::: "memory");          \
        else                asm volatile("s_waitcnt vmcnt(0)" ::: "memory");          \
        __builtin_amdgcn_s_barrier();                                                 \
        /* ---- phase 2: kk1, m0-3 ---- */                                            \
        _Pragma("unroll") for (int m = 0; m < 4; ++m) a[m] = *(const bf16x8*)(A1 + aoff[m]); \
        _Pragma("unroll") for (int n = 0; n < 4; ++n) b[n] = *(const bf16x8*)(B1 + boff[n]); \
        if (kt + 2 < (NK)) { STA(p, kt + 2, 0); }                                     \
        asm volatile("s_waitcnt lgkmcnt(0)" ::: "memory");                            \
        __builtin_amdgcn_sched_barrier(0);                                            \
        __builtin_amdgcn_s_setprio(1);                                                \
        _Pragma("unroll") for (int m = 0; m < 4; ++m)                                 \
            _Pragma("unroll") for (int n = 0; n < 4; ++n)                             \
                acc[m][n] = __builtin_amdgcn_mfma_f32_16x16x32_bf16(a[m], b[n], acc[m][n], 0, 0, 0); \
        __builtin_amdgcn_s_setprio(0);                                                \
        __builtin_amdgcn_sched_barrier(0);                                            \
        __builtin_amdgcn_s_barrier();                                                 \
        /* ---- phase 3: kk1, m4-7 ---- */                                            \
        _Pragma("unroll") for (int m = 0; m < 4; ++m) a[m] = *(const bf16x8*)(A1 + aoff[m + 4]); \
        if (kt + 2 < (NK)) { STB(p, kt + 2, 0); }                                     \
        asm volatile("s_waitcnt lgkmcnt(0)" ::: "memory");                            \
        __builtin_amdgcn_sched_barrier(0);                                            \
        __builtin_amdgcn_s_setprio(1);                                                \
        _Pragma("unroll") for (int m = 0; m < 4; ++m)                                 \
            _Pragma("unroll") for (int n = 0; n < 4; ++n)                             \
                acc[m + 4][n] = __builtin_amdgcn_mfma_f32_16x16x32_bf16(a[m], b[n], acc[m + 4][n], 0, 0, 0); \
        __builtin_amdgcn_s_setprio(0);                                                \
        __builtin_amdgcn_sched_barrier(0);                                            \
        if (kt < (NK) - 1) {                                                          \
            if (kt <= (NK) - 3) asm volatile("s_waitcnt vmcnt(8)" ::: "memory");      \
            else                asm volatile("s_waitcnt vmcnt(0)" ::: "memory");      \
            __builtin_amdgcn_s_barrier();                                             \
        }                                                                             \
    }

// ============ GEMM1: H = gelu(Xg @ w1^T + b1) [256x256, 4-phase pipe] ============
__global__ __launch_bounds__(512, 2) void k_gemm1(const u16* __restrict__ xb,
                                                  const u16* __restrict__ w1b,
                                                  const float* __restrict__ b1,
                                                  const int* __restrict__ tok_idx,
                                                  const Ctrl* __restrict__ ctrl,
                                                  u16* __restrict__ H) {
    int t = blockIdx.x;
    if (t >= ctrl->n_tiles) return;
    int e = ctrl->tile_expert[t];
    int rbase = ctrl->tile_base[t];
    int n0 = blockIdx.y * TILE;

    __shared__ __align__(16) u16 sA[2 * 2 * REG];
    __shared__ __align__(16) u16 sB[2 * 2 * REG];

    int tid = threadIdx.x;
    const u16* aS[2];
    const u16* bS[2];
    int fo[2];
#pragma unroll
    for (int q = 0; q < 2; ++q) {
        int f = q * 512 + tid;
        int row = f >> 2;
        int lc = (f & 3) ^ ((row >> 1) & 3);   // inverse-swizzled source chunk
        aS[q] = xb + (size_t)tok_idx[rbase + row] * DMODEL + lc * 8;
        bS[q] = w1b + (size_t)e * DFF * DMODEL + (size_t)(n0 + row) * DMODEL + lc * 8;
        fo[q] = f * 8;
    }

#define STA1(pp, kt, h)                                                               \
    do { _Pragma("unroll") for (int q = 0; q < 2; ++q)                                \
        load16(aS[q] + (kt) * 64 + (h) * 32, &sA[((pp) * 2 + (h)) * REG + fo[q]]); } while (0)
#define STB1(pp, kt, h)                                                               \
    do { _Pragma("unroll") for (int q = 0; q < 2; ++q)                                \
        load16(bS[q] + (kt) * 64 + (h) * 32, &sB[((pp) * 2 + (h)) * REG + fo[q]]); } while (0)

    int lane = tid & 63, w = tid >> 6;
    int wr = w >> 2, wc = w & 3;               // 2M x 4N waves; wave tile 128x64
    int l15 = lane & 15, lg = lane >> 4;
    int csw = (lg ^ ((l15 >> 1) & 3)) * 8;

    int aoff[8], boff[4];
#pragma unroll
    for (int m = 0; m < 8; ++m) aoff[m] = (wr * 128 + m * 16 + l15) * 32 + csw;
#pragma unroll
    for (int n = 0; n < 4; ++n) boff[n] = (wc * 64 + n * 16 + l15) * 32 + csw;

    f32x4 acc[8][4];
#pragma unroll
    for (int m = 0; m < 8; ++m)
#pragma unroll
        for (int n = 0; n < 4; ++n) acc[m][n] = (f32x4){0.f, 0.f, 0.f, 0.f};

    KLOOP_PHASES(STA1, STB1, DMODEL / 64)
#undef STA1
#undef STB1

    float bias[4];
#pragma unroll
    for (int n = 0; n < 4; ++n) bias[n] = b1[e * DFF + n0 + wc * 64 + n * 16 + l15];
#pragma unroll
    for (int m = 0; m < 8; ++m)
#pragma unroll
        for (int n = 0; n < 4; ++n) {
            int gcol = n0 + wc * 64 + n * 16 + l15;
#pragma unroll
            for (int r = 0; r < 4; ++r) {
                int grow = wr * 128 + m * 16 + lg * 4 + r;
                float h = acc[m][n][r] + bias[n];
                H[(size_t)(rbase + grow) * DFF + gcol] = f2bf(gelu_fast(h));
            }
        }
}

// ============ GEMM2: y += w * (H @ w2^T + b2) [256x256, 4-phase pipe] ============
__global__ __launch_bounds__(512, 2) void k_gemm2(const u16* __restrict__ H,
                                                  const u16* __restrict__ w2b,
                                                  const float* __restrict__ b2,
                                                  const int* __restrict__ tok_idx,
                                                  const float* __restrict__ tok_w,
                                                  const Ctrl* __restrict__ ctrl,
                                                  float* __restrict__ y) {
    int t = blockIdx.x;
    if (t >= ctrl->n_tiles) return;
    int e = ctrl->tile_expert[t];
    int rbase = ctrl->tile_base[t];
    int valid = ctrl->tile_valid[t];
    int n0 = blockIdx.y * TILE;

    __shared__ __align__(16) u16 sA[2 * 2 * REG];
    __shared__ __align__(16) u16 sB[2 * 2 * REG];

    int tid = threadIdx.x;
    const u16* aS[2];
    const u16* bS[2];
    int fo[2];
#pragma unroll
    for (int q = 0; q < 2; ++q) {
        int f = q * 512 + tid;
        int row = f >> 2;
        int lc = (f & 3) ^ ((row >> 1) & 3);
        aS[q] = H + (size_t)(rbase + row) * DFF + lc * 8;
        bS[q] = w2b + (size_t)e * DMODEL * DFF + (size_t)(n0 + row) * DFF + lc * 8;
        fo[q] = f * 8;
    }

#define STA2(pp, kt, h)                                                               \
    do { _Pragma("unroll") for (int q = 0; q < 2; ++q)                                \
        load16(aS[q] + (kt) * 64 + (h) * 32, &sA[((pp) * 2 + (h)) * REG + fo[q]]); } while (0)
#define STB2(pp, kt, h)                                                               \
    do { _Pragma("unroll") for (int q = 0; q < 2; ++q)                                \
        load16(bS[q] + (kt) * 64 + (h) * 32, &sB[((pp) * 2 + (h)) * REG + fo[q]]); } while (0)

    int lane = tid & 63, w = tid >> 6;
    int wr = w >> 2, wc = w & 3;
    int l15 = lane & 15, lg = lane >> 4;
    int csw = (lg ^ ((l15 >> 1) & 3)) * 8;

    int aoff[8], boff[4];
#pragma unroll
    for (int m = 0; m < 8; ++m) aoff[m] = (wr * 128 + m * 16 + l15) * 32 + csw;
#pragma unroll
    for (int n = 0; n < 4; ++n) boff[n] = (wc * 64 + n * 16 + l15) * 32 + csw;

    f32x4 acc[8][4];
#pragma unroll
    for (int m = 0; m < 8; ++m)
#pragma unroll
        for (int n = 0; n < 4; ++n) acc[m][n] = (f32x4){0.f, 0.f, 0.f, 0.f};

    KLOOP_PHASES(STA2, STB2, DFF / 64)
#undef STA2
#undef STB2

    float bias[4];
#pragma unroll
    for (int n = 0; n < 4; ++n) bias[n] = b2[e * DMODEL + n0 + wc * 64 + n * 16 + l15];
#pragma unroll
    for (int m = 0; m < 8; ++m)
#pragma unroll
        for (int n = 0; n < 4; ++n) {
            int gcol = n0 + wc * 64 + n * 16 + l15;
#pragma unroll
            for (int r = 0; r < 4; ++r) {
                int grow = wr * 128 + m * 16 + lg * 4 + r;
                if (grow < valid) {
                    int slot = rbase + grow;
                    int tok = tok_idx[slot];
                    float wgt = tok_w[slot];
                    unsafeAtomicAdd(&y[(size_t)tok * DMODEL + gcol],
                                    wgt * (acc[m][n][r] + bias[n]));
                }
            }
        }
}

// ---------------- finalize ----------------
__global__ void k_final(const Ctrl* __restrict__ ctrl, float* __restrict__ out) {
    if (blockIdx.x == 0 && threadIdx.x == 0) {
        float imp[NEXP], ld[NEXP];
        float imps = 0.f, loads = 0.f;
        for (int e = 0; e < NEXP; ++e) {
            imp[e] = ctrl->imp[e];
            ld[e] = (float)ctrl->counts[e];
            imps += imp[e];
            loads += ld[e];
        }
        float bal = 0.f;
        for (int e = 0; e < NEXP; ++e)
            bal += (imp[e] / (imps + MOE_EPS)) * (ld[e] / (loads + MOE_EPS));
        bal *= (float)NEXP;
        float z = ctrl->zacc / (float)NTOK;
        float aux = 0.01f * bal + 0.001f * z;
        size_t base = (size_t)NTOK * DMODEL;
        out[base] = aux;
        for (int e = 0; e < NEXP; ++e) out[base + 1 + e] = ld[e];
        for (int e = 0; e < NEXP; ++e) out[base + 9 + e] = imp[e];
    }
}

extern "C" void kernel_launch(void* const* d_in, const int* in_sizes, int n_in,
                              void* d_out, int out_size, void* d_ws, size_t ws_size,
                              hipStream_t stream) {
    (void)in_sizes; (void)n_in; (void)out_size; (void)ws_size;
    const float* x  = (const float*)d_in[0];
    const float* rw = (const float*)d_in[1];
    const float* w1 = (const float*)d_in[2];
    const float* b1 = (const float*)d_in[3];
    const float* w2 = (const float*)d_in[4];
    const float* b2 = (const float*)d_in[5];
    float* out = (float*)d_out;

    char* p = (char*)d_ws;
    Ctrl* ctrl = (Ctrl*)p;          p += 4096;
    u16* xb    = (u16*)p;           p += (size_t)NTOK * DMODEL * 2;
    u16* w1b   = (u16*)p;           p += (size_t)NEXP * DFF * DMODEL * 2;
    u16* w2b   = (u16*)p;           p += (size_t)NEXP * DMODEL * DFF * 2;
    u16* Hbuf  = (u16*)p;           p += (size_t)MAXROWS * DFF * 2;
    int* tok_idx = (int*)p;         p += (size_t)MAXROWS * 4;
    float* tok_w = (float*)p;       p += (size_t)MAXROWS * 4;
    int* tIdx  = (int*)p;           p += (size_t)NTOK * 2 * 4;
    float* tW  = (float*)p;         p += (size_t)NTOK * 2 * 4;

    hipMemsetAsync(ctrl, 0, sizeof(Ctrl), stream);
    hipMemsetAsync(d_out, 0, (size_t)NTOK * DMODEL * sizeof(float), stream);

    k_convert<<<2048, 256, 0, stream>>>(w1, w1b, NEXP * DFF * DMODEL / 4);
    k_convert<<<2048, 256, 0, stream>>>(w2, w2b, NEXP * DMODEL * DFF / 4);

    k_router<<<NTOK / 4, 256, 0, stream>>>(x, rw, xb, tIdx, tW, ctrl);
    k_build<<<1, 256, 0, stream>>>(tIdx, ctrl, tok_idx, tok_w);
    k_fill<<<NTOK / 256, 256, 0, stream>>>(tIdx, tW, ctrl, tok_idx, tok_w);

    dim3 g1(MAXTILES, DFF / TILE);
    k_gemm1<<<g1, 512, 0, stream>>>(xb, w1b, b1, tok_idx, ctrl, Hbuf);

    dim3 g2(MAXTILES, DMODEL / TILE);
    k_gemm2<<<g2, 512, 0, stream>>>(Hbuf, w2b, b2, tok_idx, tok_w, ctrl, out);

    k_final<<<1, 64, 0, stream>>>(ctrl, out);
}